// Round 7
// baseline (201.466 us; speedup 1.0000x reference)
//
#include <hip/hip_runtime.h>
#include <hip/hip_fp16.h>

#define N_PTS 100000
#define MU_F  100.0f
#define BUCKET 8192

typedef unsigned int uint;
typedef _Float16 h2 __attribute__((ext_vector_type(2)));

#define E_SCALE 16384.0f
#define E_SCALE_INV (1.0f / 16384.0f)

// ---------------------------------------------------------------------------
// K1 fused prep: [0,256) encode | [256,1819) transpose->2 split tables |
// [1819,1917) bucketed counting-sort scatter (no hist prescan needed)
// ---------------------------------------------------------------------------
#define ENC_BLKS 256
#define TR_BLKS  1563            // ceil(100000/64)
#define SC_BLKS  98              // 98*1024 >= 100000

__global__ __launch_bounds__(256) void k_prep(const float* __restrict__ x,
                                              const float* __restrict__ encW,
                                              const float* __restrict__ encB,
                                              const float* __restrict__ dec,
                                              const int* __restrict__ labels,
                                              float* __restrict__ enc,
                                              __half* __restrict__ decT0,
                                              __half* __restrict__ decT1,
                                              int* __restrict__ gcur,
                                              int* __restrict__ perm) {
    int b = blockIdx.x;
    if (b < ENC_BLKS) {
        // ----- encode: enc[row] = x . encW[row,:] + encB[row]
        int row = b & 31;
        int chunk = b >> 5;              // 0..7
        const int CH = N_PTS / 8;        // 12500
        int base = chunk * CH;
        const float4* W4 = reinterpret_cast<const float4*>(encW + (size_t)row * N_PTS + base);
        const float4* x4 = reinterpret_cast<const float4*>(x + base);
        const int nv = CH / 4;           // 3125
        float acc = 0.f;
        for (int idx = threadIdx.x; idx < nv; idx += 256) {
            float4 w = W4[idx];
            float4 xv = x4[idx];
            acc += w.x * xv.x + w.y * xv.y + w.z * xv.z + w.w * xv.w;
        }
        #pragma unroll
        for (int off = 32; off > 0; off >>= 1) acc += __shfl_down(acc, off);
        __shared__ float sred[4];
        int wid = threadIdx.x >> 6;
        if ((threadIdx.x & 63) == 0) sred[wid] = acc;
        __syncthreads();
        if (threadIdx.x == 0) {
            float s = sred[0] + sred[1] + sred[2] + sred[3];
            if (chunk == 0) s += encB[row];
            atomicAdd(enc + row, s);
        }
    } else if (b < ENC_BLKS + TR_BLKS) {
        // ----- transpose dec [32,N] f32 -> decT0 [N,16] (i 0..15), decT1 [N,16]
        __shared__ float tile[32][65];
        int j0 = (b - ENC_BLKS) * 64;
        int col = threadIdx.x & 63;
        int r0 = threadIdx.x >> 6;       // 0..3
        #pragma unroll
        for (int it = 0; it < 8; ++it) {
            int row = it * 4 + r0;
            int j = j0 + col;
            float v = (j < N_PTS) ? dec[(size_t)row * N_PTS + j] : 0.f;
            tile[row][col] = v;
        }
        __syncthreads();
        #pragma unroll
        for (int it = 0; it < 4; ++it) {
            int idx = it * 256 + threadIdx.x;
            int j = idx >> 4;            // 0..63
            int p = idx & 15;            // i-pair
            int jj = j0 + j;
            if (jj < N_PTS) {
                __half2 h = __halves2half2(__float2half(tile[2 * p][j]),
                                           __float2half(tile[2 * p + 1][j]));
                if (p < 8)
                    *reinterpret_cast<__half2*>(decT0 + (size_t)jj * 16 + 2 * p) = h;
                else
                    *reinterpret_cast<__half2*>(decT1 + (size_t)jj * 16 + 2 * (p - 8)) = h;
            }
        }
    } else {
        // ----- bucketed scatter: perm[c*BUCKET + pos] = j (order arbitrary)
        __shared__ int lh[16], lbase[16], lcur[16];
        const int CHUNK = 1024;
        int start = (b - ENC_BLKS - TR_BLKS) * CHUNK;
        int end = min(start + CHUNK, N_PTS);
        if (threadIdx.x < 16) { lh[threadIdx.x] = 0; lcur[threadIdx.x] = 0; }
        __syncthreads();
        for (int j = start + threadIdx.x; j < end; j += 256)
            atomicAdd(&lh[labels[j]], 1);
        __syncthreads();
        if (threadIdx.x < 16)
            lbase[threadIdx.x] = threadIdx.x * BUCKET +
                                 atomicAdd(&gcur[threadIdx.x], lh[threadIdx.x]);
        __syncthreads();
        for (int j = start + threadIdx.x; j < end; j += 256) {
            int c = labels[j];
            int lpos = atomicAdd(&lcur[c], 1);
            perm[lbase[c] + lpos] = j;
        }
    }
}

// ---------------------------------------------------------------------------
// helper: thread i<32 computes invL[i] = 1/(sigmoid(enc.bw_w[i*16+c])*MU/60)^2
// ---------------------------------------------------------------------------
__device__ inline void build_invC(const float* __restrict__ encL,
                                  const float* __restrict__ bw_w,
                                  const float* __restrict__ bw_b,
                                  float* __restrict__ invCL, int c) {
    if (threadIdx.x < 32) {
        int r = threadIdx.x * 16 + c;
        float z = bw_b[r];
        const float* wr = bw_w + r * 32;
        #pragma unroll
        for (int p = 0; p < 32; ++p) z = fmaf(encL[p], wr[p], z);
        float s = 1.f / (1.f + __expf(-z));
        float wmu = s * (MU_F / 60.0f);
        invCL[threadIdx.x] = 1.f / (wmu * wmu);
    }
}

// ---------------------------------------------------------------------------
// K2: S partials, single nd pass, 1-deep prefetch on the perm->nd chain.
// block = (c, ch): 16 x 64 = 1024 blocks x 256 thr.
// ---------------------------------------------------------------------------
__global__ __launch_bounds__(256, 4) void k_S_sorted(const float* __restrict__ enc_g,
                                                     const float* __restrict__ bw_w,
                                                     const float* __restrict__ bw_b,
                                                     const float* __restrict__ nd,
                                                     const int* __restrict__ perm,
                                                     const int* __restrict__ gcur,
                                                     float* __restrict__ S,
                                                     float* __restrict__ S_part) {
    __shared__ float encL[32], invCL[32];
    __shared__ float Sloc[1024];
    int b = blockIdx.x;
    int c = b & 15;
    int ch = b >> 4;                     // 0..63
    if (threadIdx.x < 32) encL[threadIdx.x] = enc_g[threadIdx.x];
    for (int t = threadIdx.x; t < 1024; t += 256) Sloc[t] = 0.f;
    __syncthreads();
    build_invC(encL, bw_w, bw_b, invCL, c);
    __syncthreads();

    float invC[32];
    #pragma unroll
    for (int i = 0; i < 32; ++i) invC[i] = invCL[i];

    int bs = c * BUCKET;
    int cnt = gcur[c];
    int lane = threadIdx.x & 63;
    int kk = lane & 31;
    int jh = lane >> 5;
    int gw = ch * 4 + (threadIdx.x >> 6);   // wave within c: 0..255
    const int nw = 64 * 4;                  // 256
    int npairs = (cnt + 1) >> 1;

    float acc[32];
    #pragma unroll
    for (int i = 0; i < 32; ++i) acc[i] = 0.f;

    if (gw < npairs) {
        int pp = gw;
        bool valid = (2 * pp + jh) < cnt;
        int p = valid ? (bs + 2 * pp + jh) : bs;
        int j = __builtin_nontemporal_load(&perm[p]);
        float d = __builtin_nontemporal_load(&nd[(size_t)j * 32 + kk]);
        while (pp < npairs) {
            int pn = pp + nw;
            // prefetch next
            bool vn = false; float dn = 0.f;
            if (pn < npairs) {
                vn = (2 * pn + jh) < cnt;
                int p2 = vn ? (bs + 2 * pn + jh) : bs;
                int jn = __builtin_nontemporal_load(&perm[p2]);
                dn = __builtin_nontemporal_load(&nd[(size_t)jn * 32 + kk]);
            }
            float d2 = valid ? d * d : 1e30f;
            #pragma unroll
            for (int i = 0; i < 32; ++i)
                acc[i] += fmaxf(fmaf(-d2, invC[i], 1.0f), 0.f);
            d = dn; valid = vn; pp = pn;
        }
    }
    #pragma unroll
    for (int i = 0; i < 32; ++i) acc[i] += __shfl_xor(acc[i], 32);
    if (jh == 0) {
        #pragma unroll
        for (int i = 0; i < 32; ++i) atomicAdd(&Sloc[i * 32 + kk], acc[i]);
    }
    __syncthreads();
    if (S_part) {
        for (int t = threadIdx.x; t < 1024; t += 256)
            S_part[(size_t)b * 1024 + t] = Sloc[t];
    } else {
        for (int t = threadIdx.x; t < 1024; t += 256) {
            float v = Sloc[t];
            if (v != 0.f) atomicAdd(&S[t], v);
        }
    }
}

// ---------------------------------------------------------------------------
// K3: reduce S_part (1024 x 1024) into S (pre-zeroed). grid 64 x 1024.
// ---------------------------------------------------------------------------
__global__ __launch_bounds__(1024) void k_S_reduce(const float* __restrict__ S_part,
                                                   float* __restrict__ S) {
    int g = blockIdx.x;                  // 0..63
    int t = threadIdx.x;                 // 0..1023
    float s = 0.f;
    #pragma unroll
    for (int u = 0; u < 16; ++u)
        s += S_part[(size_t)(g * 16 + u) * 1024 + t];
    atomicAdd(&S[t], s);
}

// ---------------------------------------------------------------------------
// K4 (main): split-table two-pass gather. Table h (3.2 MB, 32B rows) fits a
// 4 MiB XCD L2 -> steady-state gather hits L2. Lane: R=lane>>1 (kk), q=lane&1
// (16B quad of the 32B row). Per pair-iter: 2 row-gathers (32 rows/instr),
// coalesced nid/nd broadcast-pair loads, fdot2 over the 8-i quad, full-wave
// reduce. Pass0 -> out, pass1 -> out2 (summed by k_add; avoids any
// same-address store->load ordering hazard between passes).
// ---------------------------------------------------------------------------
__global__ __launch_bounds__(256, 4) void k_main(const float* __restrict__ enc_g,
                                                 const float* __restrict__ bw_w,
                                                 const float* __restrict__ bw_b,
                                                 const float* __restrict__ S_g,
                                                 const float* __restrict__ nd,
                                                 const int* __restrict__ nid,
                                                 const int* __restrict__ perm,
                                                 const int* __restrict__ gcur,
                                                 const __half* __restrict__ decT0,
                                                 const __half* __restrict__ decT1,
                                                 float* __restrict__ out,
                                                 float* __restrict__ out2) {
    __shared__ float encL[32], invCL[32];
    __shared__ float ELf[1024];          // E[i][kk] * E_SCALE
    int c = blockIdx.x & 15;
    int ch = blockIdx.x >> 4;            // 0..63
    if (threadIdx.x < 32) encL[threadIdx.x] = enc_g[threadIdx.x];
    __syncthreads();
    build_invC(encL, bw_w, bw_b, invCL, c);
    for (int t = threadIdx.x; t < 1024; t += 256)
        ELf[t] = encL[t >> 5] / S_g[t] * E_SCALE;
    __syncthreads();

    int lane = threadIdx.x & 63;
    int R = lane >> 1;                   // kk 0..31
    int q = lane & 1;                    // 16B quad / 8-i group

    float invA[8], invB[8];
    h2 EA[4], EB[4];
    #pragma unroll
    for (int t = 0; t < 8; ++t) {
        invA[t] = invCL[q * 8 + t];
        invB[t] = invCL[16 + q * 8 + t];
    }
    #pragma unroll
    for (int t = 0; t < 4; ++t) {
        int i0 = q * 8 + 2 * t;
        EA[t] = __builtin_bit_cast(h2, __builtin_amdgcn_cvt_pkrtz(
                    ELf[i0 * 32 + R], ELf[(i0 + 1) * 32 + R]));
        EB[t] = __builtin_bit_cast(h2, __builtin_amdgcn_cvt_pkrtz(
                    ELf[(16 + i0) * 32 + R], ELf[(16 + i0 + 1) * 32 + R]));
    }

    int bs = c * BUCKET;
    int cnt = gcur[c];
    int wv = ch * 4 + (threadIdx.x >> 6);   // wave within c: 0..255
    const int nw = 64 * 4;                  // 256
    int npairs = (cnt + 1) >> 1;
    if (wv >= npairs) return;

    auto load_pair = [&](int pp, int& j0, int& j1, bool& v1) {
        bool ok = pp < npairs;
        int p0 = ok ? (bs + 2 * pp) : bs;
        v1 = ok && ((2 * pp + 1) < cnt);
        j0 = perm[p0];
        j1 = perm[v1 ? p0 + 1 : p0];
    };
    auto load_ids = [&](int j0, int j1, int& i0, int& i1, float& d0, float& d1) {
        size_t x0 = (size_t)j0 * 32 + R;
        size_t x1 = (size_t)j1 * 32 + R;
        i0 = __builtin_nontemporal_load(&nid[x0]);
        d0 = __builtin_nontemporal_load(&nd[x0]);
        i1 = __builtin_nontemporal_load(&nid[x1]);
        d1 = __builtin_nontemporal_load(&nd[x1]);
    };

    auto run_half = [&](const uint4* __restrict__ decQ,
                        const float* inv, const h2* E,
                        float* __restrict__ ob) {
        int pp = wv;
        int j0a, j1a, j0b, j1b; bool v1a, v1b;
        int ida0, ida1; float dda0, dda1;
        load_pair(pp, j0a, j1a, v1a);
        load_ids(j0a, j1a, ida0, ida1, dda0, dda1);
        load_pair(pp + nw, j0b, j1b, v1b);
        while (pp < npairs) {
            uint4 r0 = decQ[(size_t)ida0 * 2 + q];
            uint4 r1 = decQ[(size_t)ida1 * 2 + q];
            int idb0, idb1; float ddb0, ddb1;
            load_ids(j0b, j1b, idb0, idb1, ddb0, ddb1);
            int j0c, j1c; bool v1c;
            load_pair(pp + 2 * nw, j0c, j1c, v1c);

            float d20 = dda0 * dda0;
            float d21 = dda1 * dda1;
            float a0 = 0.f, a1 = 0.f;
            #pragma unroll
            for (int t = 0; t < 4; ++t) {
                uint dw0 = (t == 0) ? r0.x : (t == 1) ? r0.y : (t == 2) ? r0.z : r0.w;
                uint dw1 = (t == 0) ? r1.x : (t == 1) ? r1.y : (t == 2) ? r1.z : r1.w;
                float i0v = inv[2 * t], i1v = inv[2 * t + 1];
                {
                    float w0 = fmaxf(fmaf(-d20, i0v, 1.f), 0.f);
                    float w1 = fmaxf(fmaf(-d20, i1v, 1.f), 0.f);
                    h2 wh = __builtin_bit_cast(h2, __builtin_amdgcn_cvt_pkrtz(w0, w1));
                    a0 = __builtin_amdgcn_fdot2(wh * E[t], __builtin_bit_cast(h2, dw0), a0, false);
                }
                {
                    float w0 = fmaxf(fmaf(-d21, i0v, 1.f), 0.f);
                    float w1 = fmaxf(fmaf(-d21, i1v, 1.f), 0.f);
                    h2 wh = __builtin_bit_cast(h2, __builtin_amdgcn_cvt_pkrtz(w0, w1));
                    a1 = __builtin_amdgcn_fdot2(wh * E[t], __builtin_bit_cast(h2, dw1), a1, false);
                }
            }
            #pragma unroll
            for (int off = 32; off > 0; off >>= 1) {
                a0 += __shfl_xor(a0, off);
                a1 += __shfl_xor(a1, off);
            }
            if (lane == 0) ob[j0a] = a0 * E_SCALE_INV;
            if (lane == 32 && v1a) ob[j1a] = a1 * E_SCALE_INV;

            j0a = j0b; j1a = j1b; v1a = v1b;
            j0b = j0c; j1b = j1c; v1b = v1c;
            ida0 = idb0; ida1 = idb1; dda0 = ddb0; dda1 = ddb1;
            pp += nw;
        }
    };

    run_half(reinterpret_cast<const uint4*>(decT0), invA, EA, out);
    run_half(reinterpret_cast<const uint4*>(decT1), invB, EB, out2);
}

// ---------------------------------------------------------------------------
// K5: out += out2
// ---------------------------------------------------------------------------
__global__ __launch_bounds__(256) void k_add(const float* __restrict__ out2,
                                             float* __restrict__ out) {
    int j = blockIdx.x * 256 + threadIdx.x;
    if (j < N_PTS) out[j] += out2[j];
}

// ---------------------------------------------------------------------------
extern "C" void kernel_launch(void* const* d_in, const int* in_sizes, int n_in,
                              void* d_out, int out_size, void* d_ws, size_t ws_size,
                              hipStream_t stream) {
    const float* x     = (const float*)d_in[0];
    const float* enc_w = (const float*)d_in[1];
    const float* enc_b = (const float*)d_in[2];
    const float* dec   = (const float*)d_in[3];
    const float* bw_w  = (const float*)d_in[4];
    const float* bw_b  = (const float*)d_in[5];
    const float* nd    = (const float*)d_in[6];
    const int*   nid   = (const int*)d_in[7];
    const int*   labels= (const int*)d_in[8];
    float* out = (float*)d_out;

    // ws layout:
    //   [0,128)               enc (32 f)
    //   [128,4224)            S (1024 f)
    //   [4224,4288)           gcur (16 i)
    //   [8192,532480)         perm (16 buckets x 8192 i, 512 KB)
    //   [532480,3732480)      decT0 (N*16 fp16, 3.2 MB)
    //   [3732480,6932480)     decT1 (N*16 fp16, 3.2 MB)
    //   [6932480,11126784)    S_part (1024*1024 f, 4 MB)    [if ws permits]
    //   [11126784,11526784)   out2 (100000 f)
    char* ws = (char*)d_ws;
    float* enc    = (float*)(ws + 0);
    float* S      = (float*)(ws + 128);
    int* gcur     = (int*)(ws + 4224);
    int* perm     = (int*)(ws + 8192);
    __half* decT0 = (__half*)(ws + 532480);
    __half* decT1 = (__half*)(ws + 3732480);
    bool use_part = ws_size >= 11526784ull;
    float* S_part = use_part ? (float*)(ws + 6932480) : nullptr;
    float* out2   = use_part ? (float*)(ws + 11126784) : (float*)(ws + 6932480);

    (void)hipMemsetAsync(d_ws, 0, 4288, stream);    // enc, S, gcur
    k_prep<<<dim3(ENC_BLKS + TR_BLKS + SC_BLKS), dim3(256), 0, stream>>>(
        x, enc_w, enc_b, dec, labels, enc, decT0, decT1, gcur, perm);
    k_S_sorted<<<dim3(1024), dim3(256), 0, stream>>>(enc, bw_w, bw_b, nd, perm,
                                                     gcur, S, S_part);
    if (use_part)
        k_S_reduce<<<dim3(64), dim3(1024), 0, stream>>>(S_part, S);
    k_main<<<dim3(1024), dim3(256), 0, stream>>>(enc, bw_w, bw_b, S, nd, nid,
                                                 perm, gcur, decT0, decT1,
                                                 out, out2);
    k_add<<<dim3((N_PTS + 255) / 256), dim3(256), 0, stream>>>(out2, out);
}

// Round 9
// 179.042 us; speedup vs baseline: 1.1252x; 1.1252x over previous
//
#include <hip/hip_runtime.h>
#include <hip/hip_fp16.h>

#define N_PTS 100000
#define MU_F  100.0f
#define BUCKET 8192

typedef unsigned int uint;
typedef _Float16 h2 __attribute__((ext_vector_type(2)));
typedef float f2 __attribute__((ext_vector_type(2)));

#define E_SCALE 16384.0f
#define E_SCALE_INV (1.0f / 16384.0f)

static __device__ inline h2 h2pack(float a, float b) {
    return __builtin_bit_cast(h2, __builtin_amdgcn_cvt_pkrtz(a, b));
}
static __device__ inline float fdot2f(h2 a, h2 b, float c) {
    return __builtin_amdgcn_fdot2(a, b, c, false);
}
static __device__ inline h2 h2fma(h2 a, h2 b, h2 c) {
#if __has_builtin(__builtin_elementwise_fma)
    return __builtin_elementwise_fma(a, b, c);
#else
    return a * b + c;
#endif
}
static __device__ inline h2 h2max(h2 a, h2 b) {
#if __has_builtin(__builtin_elementwise_max)
    return __builtin_elementwise_max(a, b);
#else
    h2 r;
    r.x = a.x > b.x ? a.x : b.x;
    r.y = a.y > b.y ? a.y : b.y;
    return r;
#endif
}

// ---------------------------------------------------------------------------
// K1 fused prep: [0,256) encode | [256,1819) transpose | [1819,1917) bucketed
// counting-sort scatter (no prescan; bucket c starts at c*BUCKET)
// ---------------------------------------------------------------------------
#define ENC_BLKS 256
#define TR_BLKS  1563            // ceil(100000/64)
#define SC_BLKS  98              // 98*1024 >= 100000

__global__ __launch_bounds__(256) void k_prep(const float* __restrict__ x,
                                              const float* __restrict__ encW,
                                              const float* __restrict__ encB,
                                              const float* __restrict__ dec,
                                              const int* __restrict__ labels,
                                              float* __restrict__ enc,
                                              __half* __restrict__ decT,
                                              int* __restrict__ gcur,
                                              int* __restrict__ perm) {
    int b = blockIdx.x;
    if (b < ENC_BLKS) {
        // ----- encode: enc[row] = x . encW[row,:] + encB[row]
        int row = b & 31;
        int chunk = b >> 5;              // 0..7
        const int CH = N_PTS / 8;        // 12500
        int base = chunk * CH;
        const float4* W4 = reinterpret_cast<const float4*>(encW + (size_t)row * N_PTS + base);
        const float4* x4 = reinterpret_cast<const float4*>(x + base);
        const int nv = CH / 4;           // 3125
        float acc = 0.f;
        for (int idx = threadIdx.x; idx < nv; idx += 256) {
            float4 w = W4[idx];
            float4 xv = x4[idx];
            acc += w.x * xv.x + w.y * xv.y + w.z * xv.z + w.w * xv.w;
        }
        #pragma unroll
        for (int off = 32; off > 0; off >>= 1) acc += __shfl_down(acc, off);
        __shared__ float sred[4];
        int wid = threadIdx.x >> 6;
        if ((threadIdx.x & 63) == 0) sred[wid] = acc;
        __syncthreads();
        if (threadIdx.x == 0) {
            float s = sred[0] + sred[1] + sred[2] + sred[3];
            if (chunk == 0) s += encB[row];
            atomicAdd(enc + row, s);
        }
    } else if (b < ENC_BLKS + TR_BLKS) {
        // ----- transpose dec [32,N] f32 -> decT [N,32] fp16 (64B rows)
        __shared__ float tile[32][65];
        int j0 = (b - ENC_BLKS) * 64;
        int col = threadIdx.x & 63;
        int r0 = threadIdx.x >> 6;       // 0..3
        #pragma unroll
        for (int it = 0; it < 8; ++it) {
            int row = it * 4 + r0;
            int j = j0 + col;
            float v = (j < N_PTS) ? dec[(size_t)row * N_PTS + j] : 0.f;
            tile[row][col] = v;
        }
        __syncthreads();
        #pragma unroll
        for (int it = 0; it < 4; ++it) {
            int idx = it * 256 + threadIdx.x;
            int j = idx >> 4;            // 0..63
            int p = idx & 15;            // i-pair
            int jj = j0 + j;
            if (jj < N_PTS) {
                __half2 h = __halves2half2(__float2half(tile[2 * p][j]),
                                           __float2half(tile[2 * p + 1][j]));
                *reinterpret_cast<__half2*>(decT + (size_t)jj * 32 + 2 * p) = h;
            }
        }
    } else {
        // ----- bucketed scatter: perm[c*BUCKET + pos] = j
        __shared__ int lh[16], lbase[16], lcur[16];
        const int CHUNK = 1024;
        int start = (b - ENC_BLKS - TR_BLKS) * CHUNK;
        int end = min(start + CHUNK, N_PTS);
        if (threadIdx.x < 16) { lh[threadIdx.x] = 0; lcur[threadIdx.x] = 0; }
        __syncthreads();
        for (int j = start + threadIdx.x; j < end; j += 256)
            atomicAdd(&lh[labels[j]], 1);
        __syncthreads();
        if (threadIdx.x < 16)
            lbase[threadIdx.x] = threadIdx.x * BUCKET +
                                 atomicAdd(&gcur[threadIdx.x], lh[threadIdx.x]);
        __syncthreads();
        for (int j = start + threadIdx.x; j < end; j += 256) {
            int c = labels[j];
            int lpos = atomicAdd(&lcur[c], 1);
            perm[lbase[c] + lpos] = j;
        }
    }
}

// ---------------------------------------------------------------------------
// helper: thread i<32 computes invL[i] = 1/(sigmoid(enc.bw_w[i*16+c])*MU/60)^2
// ---------------------------------------------------------------------------
__device__ inline void build_invC(const float* __restrict__ encL,
                                  const float* __restrict__ bw_w,
                                  const float* __restrict__ bw_b,
                                  float* __restrict__ invCL, int c) {
    if (threadIdx.x < 32) {
        int r = threadIdx.x * 16 + c;
        float z = bw_b[r];
        const float* wr = bw_w + r * 32;
        #pragma unroll
        for (int p = 0; p < 32; ++p) z = fmaf(encL[p], wr[p], z);
        float s = 1.f / (1.f + __expf(-z));
        float wmu = s * (MU_F / 60.0f);
        invCL[threadIdx.x] = 1.f / (wmu * wmu);
    }
}

// ---------------------------------------------------------------------------
// K2: S partials, float2-packed inner (v_pk_fma_f32), 2-deep prefetch.
// block = (c, ch): 16 x 64 = 1024 blocks x 256 thr.
// ---------------------------------------------------------------------------
__global__ __launch_bounds__(256, 4) void k_S_sorted(const float* __restrict__ enc_g,
                                                     const float* __restrict__ bw_w,
                                                     const float* __restrict__ bw_b,
                                                     const float* __restrict__ nd,
                                                     const int* __restrict__ perm,
                                                     const int* __restrict__ gcur,
                                                     float* __restrict__ S,
                                                     float* __restrict__ S_part) {
    __shared__ float encL[32], invCL[32];
    __shared__ float Sloc[1024];
    int b = blockIdx.x;
    int c = b & 15;
    int ch = b >> 4;                     // 0..63
    if (threadIdx.x < 32) encL[threadIdx.x] = enc_g[threadIdx.x];
    for (int t = threadIdx.x; t < 1024; t += 256) Sloc[t] = 0.f;
    __syncthreads();
    build_invC(encL, bw_w, bw_b, invCL, c);
    __syncthreads();

    f2 inv2[16];
    #pragma unroll
    for (int t = 0; t < 16; ++t) { inv2[t].x = invCL[2 * t]; inv2[t].y = invCL[2 * t + 1]; }

    int bs = c * BUCKET;
    int cnt = gcur[c];
    int lane = threadIdx.x & 63;
    int kk = lane & 31;
    int jh = lane >> 5;
    int gw = ch * 4 + (threadIdx.x >> 6);   // wave within c: 0..255
    const int nw = 64 * 4;                  // 256
    int npairs = (cnt + 1) >> 1;

    f2 acc2[16];
    #pragma unroll
    for (int t = 0; t < 16; ++t) { acc2[t].x = 0.f; acc2[t].y = 0.f; }

    if (gw < npairs) {
        auto ld = [&](int pc, float& d, bool& v) {
            bool ok = pc < npairs;
            v = ok && (2 * pc + jh) < cnt;
            int p = v ? (bs + 2 * pc + jh) : bs;
            int j = __builtin_nontemporal_load(&perm[p]);
            d = __builtin_nontemporal_load(&nd[(size_t)j * 32 + kk]);
        };
        int pp = gw;
        float dA, dB; bool vA, vB;
        ld(pp, dA, vA);
        ld(pp + nw, dB, vB);
        while (pp < npairs) {
            float dC; bool vC;
            ld(pp + 2 * nw, dC, vC);
            float d2 = vA ? dA * dA : 1e30f;
            f2 md2; md2.x = -d2; md2.y = -d2;
            f2 onev; onev.x = 1.f; onev.y = 1.f;
            #pragma unroll
            for (int t = 0; t < 16; ++t) {
                f2 w = md2 * inv2[t] + onev;     // v_pk_fma_f32
                w.x = fmaxf(w.x, 0.f);
                w.y = fmaxf(w.y, 0.f);
                acc2[t] += w;                    // v_pk_add_f32
            }
            dA = dB; vA = vB; dB = dC; vB = vC;
            pp += nw;
        }
    }
    #pragma unroll
    for (int t = 0; t < 16; ++t) {
        acc2[t].x += __shfl_xor(acc2[t].x, 32);
        acc2[t].y += __shfl_xor(acc2[t].y, 32);
    }
    if (jh == 0) {
        #pragma unroll
        for (int t = 0; t < 16; ++t) {
            atomicAdd(&Sloc[(2 * t) * 32 + kk], acc2[t].x);
            atomicAdd(&Sloc[(2 * t + 1) * 32 + kk], acc2[t].y);
        }
    }
    __syncthreads();
    if (S_part) {
        for (int t = threadIdx.x; t < 1024; t += 256)
            S_part[(size_t)b * 1024 + t] = Sloc[t];
    } else {
        for (int t = threadIdx.x; t < 1024; t += 256) {
            float v = Sloc[t];
            if (v != 0.f) atomicAdd(&S[t], v);
        }
    }
}

// ---------------------------------------------------------------------------
// K3: reduce S_part (1024 x 1024) into S (pre-zeroed). grid 64 x 1024.
// ---------------------------------------------------------------------------
__global__ __launch_bounds__(1024) void k_S_reduce(const float* __restrict__ S_part,
                                                   float* __restrict__ S) {
    int g = blockIdx.x;                  // 0..63
    int t = threadIdx.x;                 // 0..1023
    float s = 0.f;
    #pragma unroll
    for (int u = 0; u < 16; ++u)
        s += S_part[(size_t)(g * 16 + u) * 1024 + t];
    atomicAdd(&S[t], s);
}

// ---------------------------------------------------------------------------
// K4 (main): round-5 quad-broadcast structure + packed-fp16 inner.
// Lane L: R=L>>2 (row sub-index 0..15), q=L&3 (16B quad of 64B decT row).
// Stage s: (jsel, kk) = (s>>1, (s&1)*16 + R). Quad lanes broadcast-load the
// same nid/nd scalar; gathers touch 16 lines/instr. Per 2 i:
// v_pk_fma_f16 + v_pk_max_f16 + v_pk_mul_f16 + v_dot2_f32_f16.
// Pipeline: j-pair 2 ahead, ids/d 1 ahead. Single pass, plain stores.
// ---------------------------------------------------------------------------
__global__ __launch_bounds__(256, 6) void k_main(const float* __restrict__ enc_g,
                                                 const float* __restrict__ bw_w,
                                                 const float* __restrict__ bw_b,
                                                 const float* __restrict__ S_g,
                                                 const float* __restrict__ nd,
                                                 const int* __restrict__ nid,
                                                 const int* __restrict__ perm,
                                                 const int* __restrict__ gcur,
                                                 const __half* __restrict__ decT,
                                                 float* __restrict__ out) {
    __shared__ float encL[32], invCL[32];
    __shared__ float ELf[1024];          // E[i][kk] * E_SCALE
    int c = blockIdx.x & 15;
    int ch = blockIdx.x >> 4;            // 0..95
    if (threadIdx.x < 32) encL[threadIdx.x] = enc_g[threadIdx.x];
    __syncthreads();
    build_invC(encL, bw_w, bw_b, invCL, c);
    for (int t = threadIdx.x; t < 1024; t += 256)
        ELf[t] = encL[t >> 5] / S_g[t] * E_SCALE;
    __syncthreads();

    int lane = threadIdx.x & 63;
    int R = lane >> 2;                   // 0..15
    int q = lane & 3;                    // i-quarter / row quad

    h2 invh[4], EhA[4], EhB[4];
    #pragma unroll
    for (int t = 0; t < 4; ++t) {
        int i0 = q * 8 + 2 * t;
        invh[t] = h2pack(fminf(invCL[i0], 6.0e4f), fminf(invCL[i0 + 1], 6.0e4f));
        EhA[t] = h2pack(ELf[i0 * 32 + R], ELf[(i0 + 1) * 32 + R]);
        EhB[t] = h2pack(ELf[i0 * 32 + R + 16], ELf[(i0 + 1) * 32 + R + 16]);
    }
    const h2 zero2 = h2pack(0.f, 0.f);
    const h2 one2 = h2pack(1.f, 1.f);

    int bs = c * BUCKET;
    int cnt = gcur[c];
    int wv = ch * 4 + (threadIdx.x >> 6);   // wave within c: 0..383
    const int nw = 96 * 4;                  // 384
    int npairs = (cnt + 1) >> 1;
    const uint4* decQ = reinterpret_cast<const uint4*>(decT);
    if (wv >= npairs) return;

    auto load_pair = [&](int pp, int& j0, int& j1, bool& v1) {
        bool ok = pp < npairs;
        int p0 = ok ? (bs + 2 * pp) : bs;
        v1 = ok && ((2 * pp + 1) < cnt);
        j0 = perm[p0];
        j1 = perm[v1 ? p0 + 1 : p0];
    };
    auto load_ids = [&](int j0, int j1, int* id, float* dd) {
        #pragma unroll
        for (int s = 0; s < 4; ++s) {
            int jj = (s >> 1) ? j1 : j0;
            size_t idx = (size_t)jj * 32 + (s & 1) * 16 + R;
            id[s] = __builtin_nontemporal_load(&nid[idx]);
            dd[s] = __builtin_nontemporal_load(&nd[idx]);
        }
    };

    int pp = wv;
    int j0a, j1a, j0b, j1b; bool v1a, v1b;
    int ida[4]; float dda[4];
    load_pair(pp, j0a, j1a, v1a);
    load_ids(j0a, j1a, ida, dda);
    load_pair(pp + nw, j0b, j1b, v1b);

    while (pp < npairs) {
        uint4 r0 = decQ[(size_t)ida[0] * 4 + q];
        uint4 r1 = decQ[(size_t)ida[1] * 4 + q];
        uint4 r2 = decQ[(size_t)ida[2] * 4 + q];
        uint4 r3 = decQ[(size_t)ida[3] * 4 + q];
        int idb[4]; float ddb[4];
        load_ids(j0b, j1b, idb, ddb);
        int j0c, j1c; bool v1c;
        load_pair(pp + 2 * nw, j0c, j1c, v1c);

        float d20 = dda[0] * dda[0];
        float d21 = dda[1] * dda[1];
        float d22 = dda[2] * dda[2];
        float d23 = dda[3] * dda[3];
        h2 md0 = h2pack(-d20, -d20);
        h2 md1 = h2pack(-d21, -d21);
        h2 md2 = h2pack(-d22, -d22);
        h2 md3 = h2pack(-d23, -d23);

        float a0 = 0.f, a1 = 0.f, a2 = 0.f, a3 = 0.f;
        #pragma unroll
        for (int t = 0; t < 4; ++t) {
            uint dw0 = (t == 0) ? r0.x : (t == 1) ? r0.y : (t == 2) ? r0.z : r0.w;
            uint dw1 = (t == 0) ? r1.x : (t == 1) ? r1.y : (t == 2) ? r1.z : r1.w;
            uint dw2 = (t == 0) ? r2.x : (t == 1) ? r2.y : (t == 2) ? r2.z : r2.w;
            uint dw3 = (t == 0) ? r3.x : (t == 1) ? r3.y : (t == 2) ? r3.z : r3.w;
            {
                h2 w = h2max(h2fma(md0, invh[t], one2), zero2);
                a0 = fdot2f(w * EhA[t], __builtin_bit_cast(h2, dw0), a0);
            }
            {
                h2 w = h2max(h2fma(md1, invh[t], one2), zero2);
                a1 = fdot2f(w * EhB[t], __builtin_bit_cast(h2, dw1), a1);
            }
            {
                h2 w = h2max(h2fma(md2, invh[t], one2), zero2);
                a2 = fdot2f(w * EhA[t], __builtin_bit_cast(h2, dw2), a2);
            }
            {
                h2 w = h2max(h2fma(md3, invh[t], one2), zero2);
                a3 = fdot2f(w * EhB[t], __builtin_bit_cast(h2, dw3), a3);
            }
        }
        float u = a0 + a1;               // j0 partial
        float v = a2 + a3;               // j1 partial
        #pragma unroll
        for (int off = 32; off > 0; off >>= 1) {
            u += __shfl_xor(u, off);
            v += __shfl_xor(v, off);
        }
        if (lane == 0) out[j0a] = u * E_SCALE_INV;
        if (lane == 32 && v1a) out[j1a] = v * E_SCALE_INV;

        j0a = j0b; j1a = j1b; v1a = v1b;
        j0b = j0c; j1b = j1c; v1b = v1c;
        #pragma unroll
        for (int s = 0; s < 4; ++s) { ida[s] = idb[s]; dda[s] = ddb[s]; }
        pp += nw;
    }
}

// ---------------------------------------------------------------------------
extern "C" void kernel_launch(void* const* d_in, const int* in_sizes, int n_in,
                              void* d_out, int out_size, void* d_ws, size_t ws_size,
                              hipStream_t stream) {
    const float* x     = (const float*)d_in[0];
    const float* enc_w = (const float*)d_in[1];
    const float* enc_b = (const float*)d_in[2];
    const float* dec   = (const float*)d_in[3];
    const float* bw_w  = (const float*)d_in[4];
    const float* bw_b  = (const float*)d_in[5];
    const float* nd    = (const float*)d_in[6];
    const int*   nid   = (const int*)d_in[7];
    const int*   labels= (const int*)d_in[8];
    float* out = (float*)d_out;

    // ws layout:
    //   [0,128)              enc (32 f)
    //   [128,4224)           S (1024 f)
    //   [4224,4288)          gcur (16 i)
    //   [8192,532480)        perm (16 buckets x 8192 i, 512 KB)
    //   [532480,6932480)     decT (N*32 fp16, 6.4 MB)
    //   [6932480,11126784)   S_part (1024*1024 f, 4 MB)  [if ws permits]
    char* ws = (char*)d_ws;
    float* enc    = (float*)(ws + 0);
    float* S      = (float*)(ws + 128);
    int* gcur     = (int*)(ws + 4224);
    int* perm     = (int*)(ws + 8192);
    __half* decT  = (__half*)(ws + 532480);
    bool use_part = ws_size >= 11126784ull;
    float* S_part = use_part ? (float*)(ws + 6932480) : nullptr;

    (void)hipMemsetAsync(d_ws, 0, 4288, stream);    // enc, S, gcur
    k_prep<<<dim3(ENC_BLKS + TR_BLKS + SC_BLKS), dim3(256), 0, stream>>>(
        x, enc_w, enc_b, dec, labels, enc, decT, gcur, perm);
    k_S_sorted<<<dim3(1024), dim3(256), 0, stream>>>(enc, bw_w, bw_b, nd, perm,
                                                     gcur, S, S_part);
    if (use_part)
        k_S_reduce<<<dim3(64), dim3(1024), 0, stream>>>(S_part, S);
    k_main<<<dim3(1536), dim3(256), 0, stream>>>(enc, bw_w, bw_b, S, nd, nid,
                                                 perm, gcur, decT, out);
}